// Round 13
// baseline (430.115 us; speedup 1.0000x reference)
//
#include <hip/hip_runtime.h>

#define E_TOTAL 1000000
#define EMB     128
#define NRBF    16
#define NATOMS  50000
#define APB     16                         // atoms per block (50000 = 3125*16)
#define NBLK    ((NATOMS + 255) / 256)     // scan blocks
#define EIDX_CACHE 1280                    // block edge-id LDS cache (mean 326, +50 sigma)

typedef _Float16 f16x8 __attribute__((ext_vector_type(8)));
typedef _Float16 f16x4 __attribute__((ext_vector_type(4)));
typedef float    f32x4 __attribute__((ext_vector_type(4)));

__device__ __forceinline__ float silu_f(float v) {
    return v * (1.0f / (1.0f + __expf(-v)));
}

// LDS row e holds sorted edge sigma(e): lane-quarter lq's C-rows across the
// 4 mt steps then cover sorted positions lq*16..lq*16+15 consecutively.
__device__ __forceinline__ int sigma64(int e) {
    return (((e & 15) >> 2) << 4) + ((e >> 4) << 2) + (e & 3);
}

// ---------------------------------------------------------------------------
// CSR build: counting sort of edge ids by destination atom.
// ---------------------------------------------------------------------------
__global__ __launch_bounds__(256)
void hist_kernel(const int* __restrict__ idnb, int* __restrict__ counts) {
    const int e = blockIdx.x * 256 + threadIdx.x;
    if (e < E_TOTAL) atomicAdd(&counts[idnb[e]], 1);
}

__global__ __launch_bounds__(256)
void scan1_kernel(const int* __restrict__ counts, int* __restrict__ row_ptr,
                  int* __restrict__ bsums) {
    __shared__ int sd[256];
    const int tid = threadIdx.x;
    const int idx = blockIdx.x * 256 + tid;
    const int v = (idx < NATOMS) ? counts[idx] : 0;
    sd[tid] = v;
    __syncthreads();
#pragma unroll
    for (int off = 1; off < 256; off <<= 1) {
        const int t = (tid >= off) ? sd[tid - off] : 0;
        __syncthreads();
        sd[tid] += t;
        __syncthreads();
    }
    if (idx < NATOMS) row_ptr[idx] = sd[tid] - v;
    if (tid == 255) bsums[blockIdx.x] = sd[255];
}

__global__ __launch_bounds__(256)
void scan2_kernel(int* __restrict__ bsums) {
    __shared__ int sd[256];
    const int tid = threadIdx.x;
    const int v = (tid < NBLK) ? bsums[tid] : 0;
    sd[tid] = v;
    __syncthreads();
#pragma unroll
    for (int off = 1; off < 256; off <<= 1) {
        const int t = (tid >= off) ? sd[tid - off] : 0;
        __syncthreads();
        sd[tid] += t;
        __syncthreads();
    }
    if (tid < NBLK) bsums[tid] = sd[tid] - v;
}

__global__ __launch_bounds__(256)
void scan3_kernel(const int* __restrict__ bsums, int* __restrict__ row_ptr,
                  int* __restrict__ cursor) {
    const int idx = blockIdx.x * 256 + threadIdx.x;
    if (idx < NATOMS) {
        const int r = row_ptr[idx] + bsums[blockIdx.x];
        row_ptr[idx] = r;
        cursor[idx]  = r;
    }
    if (idx == 0) row_ptr[NATOMS] = E_TOTAL;
}

__global__ __launch_bounds__(256)
void scatter_kernel(const int* __restrict__ idnb, int* __restrict__ cursor,
                    int* __restrict__ eidx) {
    const int e = blockIdx.x * 256 + threadIdx.x;
    if (e < E_TOTAL) {
        const int a = idnb[e];
        const int p = atomicAdd(&cursor[a], 1);
        eidx[p] = e;
    }
}

// ---------------------------------------------------------------------------
// MFMA edge kernel. Minimal-fence staging: the barrier-bracketed region is
// only {4x ds_write_b128 + 1x ds_write_b64 + sAid}; f32->f16 cvt + rel-atom
// math run in the compute phase; one eidx per lane from an LDS cache.
// Row-per-lane granule layout: lane (row=tid>>2, gc=tid&3 +4i), 128B-coalesced
// gather per 4 lanes. Wx split-f16 (precision anchor); Wr single-f16.
// sigma-permuted C-rows + carried run-merge + fused gate (r11-proven).
// ---------------------------------------------------------------------------
__global__ __launch_bounds__(256)
void edge_kernel(const float* __restrict__ x,
                 const float* __restrict__ rbf,
                 const int*   __restrict__ eidx,
                 const int*   __restrict__ row_ptr,
                 const float* __restrict__ Wx,
                 const float* __restrict__ bx,
                 const float* __restrict__ Wr,
                 const float* __restrict__ br,
                 const float* __restrict__ c_a,
                 const float* __restrict__ c_b,
                 const float* __restrict__ c_x,
                 float* __restrict__ acc)
{
    __shared__ _Float16 sX[64 * 128];   // 16 KB, XOR-swizzled 8-f16 granules
    __shared__ _Float16 sR[64 * 40];    // 5 KB, stride-40 pad, k>=16 zero
    __shared__ float    sAcc[APB][132]; // 8.4 KB
    __shared__ int      sEidx[EIDX_CACHE]; // 5 KB block edge-id cache
    __shared__ int      sAid[64];       // rel-atom of sorted pos (tile-local)

    const int tid  = threadIdx.x;
    const int w    = tid >> 6;
    const int lane = tid & 63;
    const int lq   = lane >> 4;
    const int lm   = lane & 15;
    const int row  = tid >> 2;          // staging row 0..63 (4 lanes/row)
    const int gcb  = tid & 3;           // granule base

    const int aBase = blockIdx.x * APB;

    // scalar row_ptr boundary table (uniform -> SGPRs)
    int rp[APB];
#pragma unroll
    for (int a = 0; a < APB; ++a) rp[a] = row_ptr[aBase + a];
    const int eBeg = rp[0];
    const int eEnd = row_ptr[aBase + APB];
    const int nEdge = eEnd - eBeg;
    const int ntile = (nEdge + 63) >> 6;

    const float ca = c_a[0];
    const float sc = c_b[0] * c_x[0];
    const int col0 = w * 32 + lm;
    const int col1 = col0 + 16;
    const float bx0 = bx[col0], bx1 = bx[col1];
    const float br0 = br[col0], br1 = br[col1];

    // ---- hoist W fragments (Wx split hi/lo; Wr single f16) ----
    f16x8 wxh[4][2], wxl[4][2], wrh[2];
#pragma unroll
    for (int ks = 0; ks < 4; ++ks)
#pragma unroll
        for (int nt = 0; nt < 2; ++nt) {
            const int n = w * 32 + nt * 16 + lm;
            f16x8 h8, l8;
#pragma unroll
            for (int j = 0; j < 8; ++j) {
                const int k = ks * 32 + lq * 8 + j;
                const float v = Wx[k * EMB + n];
                const _Float16 hv = (_Float16)v;
                h8[j] = hv;
                l8[j] = (_Float16)(v - (float)hv);
            }
            wxh[ks][nt] = h8;
            wxl[ks][nt] = l8;
        }
#pragma unroll
    for (int nt = 0; nt < 2; ++nt) {
        const int n = w * 32 + nt * 16 + lm;
        f16x8 h8;
#pragma unroll
        for (int j = 0; j < 8; ++j) {
            const int k = lq * 8 + j;
            h8[j] = (_Float16)((k < NRBF) ? Wr[k * EMB + n] : 0.f);
        }
        wrh[nt] = h8;
    }

    // init LDS: zero accumulator; zero sR k in [16,40); fill edge-id cache
    for (int f = tid; f < APB * 132; f += 256) ((float*)sAcc)[f] = 0.f;
    for (int f = tid; f < 64 * 24; f += 256)
        sR[(f / 24) * 40 + 16 + (f % 24)] = (_Float16)0.f;
    for (int f = tid; f < EIDX_CACHE; f += 256)
        sEidx[f] = (f < nEdge) ? eidx[eBeg + f] : 0;
    __syncthreads();                    // sEidx ready

    float4 px[8];                       // f32 in-flight (one tile)
    f16x8  pxh[4];                      // converted, held for write
    f16x4  prh;
    int    prel = -1;

    // issue the 9 gather loads for tile t (one eidx per lane, LDS-cached)
    auto issue = [&](int t) {
        const int nb = eBeg + t * 64;
        int p = nb + sigma64(row);
        p = min(p, eEnd - 1);
        const int off = p - eBeg;
        const int eid = (off < EIDX_CACHE) ? sEidx[off] : eidx[p];
        const float* xr = x + (size_t)eid * EMB;
#pragma unroll
        for (int i = 0; i < 4; ++i) {
            const int k0 = (gcb + 4 * i) * 8;
            px[2 * i]     = *(const float4*)(xr + k0);
            px[2 * i + 1] = *(const float4*)(xr + k0 + 4);
        }
        // rbf: same row -> same eid; 4 lanes cover k 0..16
        // (reuse px path's eid; load into a temp float4 folded into cvt below)
    };

    // convert tile t's data to f16 + compute rel-atom (runs in compute phase)
    auto convert = [&](int t) {
        const int nb = eBeg + t * 64;
        {
            int p = nb + sigma64(row);
            p = min(p, eEnd - 1);
            const int off = p - eBeg;
            const int eid = (off < EIDX_CACHE) ? sEidx[off] : eidx[p];
            const float4 pr = *(const float4*)(rbf + (size_t)eid * NRBF + gcb * 4);
            prh = f16x4{(_Float16)(pr.x * ca), (_Float16)(pr.y * ca),
                        (_Float16)(pr.z * ca), (_Float16)(pr.w * ca)};
        }
#pragma unroll
        for (int i = 0; i < 4; ++i) {
            const float4 a = px[2 * i];
            const float4 b = px[2 * i + 1];
            pxh[i] = f16x8{(_Float16)a.x, (_Float16)a.y, (_Float16)a.z, (_Float16)a.w,
                           (_Float16)b.x, (_Float16)b.y, (_Float16)b.z, (_Float16)b.w};
        }
        if (tid < 64) {
            const int pos = nb + tid;
            if (pos >= eEnd) {
                prel = -1;
            } else {
                int rel = 0;
#pragma unroll
                for (int a = 1; a < APB; ++a) rel += (pos >= rp[a]) ? 1 : 0;
                prel = rel;
            }
        }
    };

    // minimal fenced region: pure LDS stores
    auto write_lds = [&]() {
#pragma unroll
        for (int i = 0; i < 4; ++i) {
            const int gc = gcb + 4 * i;
            const int idx = (row * 128 + gc * 8) ^ ((row & 7) << 3);
            *(f16x8*)&sX[idx] = pxh[i];
        }
        *(f16x4*)&sR[row * 40 + gcb * 4] = prh;
        if (tid < 64) sAid[tid] = prel;
    };

    if (ntile > 0) {
        issue(0);
        convert(0);                     // waits the tile-0 loads
        if (ntile > 1) issue(1);
    }

    for (int t = 0; t < ntile; ++t) {
        write_lds();                    // tile t (pxh/prh/prel ready)
        __syncthreads();                // tile t visible

        if (t + 1 < ntile) {
            convert(t + 1);             // vmcnt-waits loads issued last iter
            if (t + 2 < ntile) issue(t + 2);   // in flight through compute
        }

        // run-merge state carried across the whole tile (16-edge span/lane)
        int   curA = -2;
        float a0v = 0.f, a1v = 0.f;

        auto epi = [&](const f32x4 hac[2], const f32x4 gac[2], int mt) {
            const int pbase = lq * 16 + mt * 4;
            float v0[4], v1[4];
#pragma unroll
            for (int r = 0; r < 4; ++r) {
                const float g0 = gac[0][r] + br0, h0 = hac[0][r] + bx0;
                const float g1 = gac[1][r] + br1, h1 = hac[1][r] + bx1;
                const float d0 = (1.f + __expf(-g0)) * (1.f + __expf(-h0));
                const float d1 = (1.f + __expf(-g1)) * (1.f + __expf(-h1));
                v0[r] = sc * g0 * h0 * __builtin_amdgcn_rcpf(d0);
                v1[r] = sc * g1 * h1 * __builtin_amdgcn_rcpf(d1);
            }
#pragma unroll
            for (int r = 0; r < 4; ++r) {
                const int rel = sAid[pbase + r];
                if (rel != curA) {                  // rarely taken (run ~20)
                    if (curA >= 0) {
                        atomicAdd(&sAcc[curA][col0], a0v);
                        atomicAdd(&sAcc[curA][col1], a1v);
                    }
                    curA = rel; a0v = 0.f; a1v = 0.f;
                }
                a0v += v0[r];
                a1v += v1[r];
            }
        };

        auto mfma_mt = [&](f32x4 hac[2], f32x4 gac[2], int mt) {
#pragma unroll
            for (int nt = 0; nt < 2; ++nt) { hac[nt] = 0.f; gac[nt] = 0.f; }
            const int m = mt * 16 + lm;
            const f16x8 rh = *(const f16x8*)&sR[m * 40 + lq * 8];
#pragma unroll
            for (int nt = 0; nt < 2; ++nt)
                gac[nt] = __builtin_amdgcn_mfma_f32_16x16x32_f16(rh, wrh[nt], gac[nt], 0, 0, 0);
#pragma unroll
            for (int ks = 0; ks < 4; ++ks) {
                const int xi = (m * 128 + ks * 32 + lq * 8) ^ ((m & 7) << 3);
                const f16x8 xh = *(const f16x8*)&sX[xi];
#pragma unroll
                for (int nt = 0; nt < 2; ++nt) {
                    hac[nt] = __builtin_amdgcn_mfma_f32_16x16x32_f16(xh, wxh[ks][nt], hac[nt], 0, 0, 0);
                    hac[nt] = __builtin_amdgcn_mfma_f32_16x16x32_f16(xh, wxl[ks][nt], hac[nt], 0, 0, 0);
                }
            }
        };

        // 2-mt groups: two independent MFMA chains per epilogue pair
#pragma unroll
        for (int g = 0; g < 2; ++g) {
            f32x4 hacA[2], gacA[2], hacB[2], gacB[2];
            mfma_mt(hacA, gacA, g * 2);
            mfma_mt(hacB, gacB, g * 2 + 1);
            epi(hacA, gacA, g * 2);
            epi(hacB, gacB, g * 2 + 1);
        }

        if (curA >= 0) {                            // final flush per tile
            atomicAdd(&sAcc[curA][col0], a0v);
            atomicAdd(&sAcc[curA][col1], a1v);
        }

        __syncthreads();                // readers of tile t done
    }

    {
        const int r = tid >> 4;
        const int c = (tid & 15) * 8;
        float* dst = acc + (size_t)(aBase + r) * EMB + c;
        *(float4*)(dst)     = *(const float4*)&sAcc[r][c];
        *(float4*)(dst + 4) = *(const float4*)&sAcc[r][c + 4];
    }
}

// ---------------------------------------------------------------------------
// MFMA atom-MLP layer: Y = silu(X @ W + b). 2 subtiles of 64 rows per block.
// ---------------------------------------------------------------------------
__global__ __launch_bounds__(256, 2)
void layer_kernel(const float* __restrict__ X,
                  const float* __restrict__ W,
                  const float* __restrict__ b,
                  float* __restrict__ Y, int M)
{
    __shared__ _Float16 sX[64 * 128];

    const int tid  = threadIdx.x;
    const int w    = tid >> 6;
    const int lane = tid & 63;
    const int lq   = lane >> 4;
    const int lm   = lane & 15;

    const int col0 = w * 32 + lm;
    const int col1 = col0 + 16;
    const float b0 = b[col0], b1 = b[col1];

    f16x8 wh[4][2], wl[4][2];
#pragma unroll
    for (int ks = 0; ks < 4; ++ks)
#pragma unroll
        for (int nt = 0; nt < 2; ++nt) {
            const int n = w * 32 + nt * 16 + lm;
            f16x8 h8, l8;
#pragma unroll
            for (int j = 0; j < 8; ++j) {
                const int k = ks * 32 + lq * 8 + j;
                const float v = W[k * EMB + n];
                const _Float16 hv = (_Float16)v;
                h8[j] = hv;
                l8[j] = (_Float16)(v - (float)hv);
            }
            wh[ks][nt] = h8;
            wl[ks][nt] = l8;
        }

#pragma unroll
    for (int sub = 0; sub < 2; ++sub) {
        const int base = blockIdx.x * 128 + sub * 64;
        __syncthreads();
#pragma unroll
        for (int i = 0; i < 8; ++i) {
            const int e = (tid >> 5) + i * 8;
            const int rowg = min(base + e, M - 1);
            const float4 v = *(const float4*)(X + (size_t)rowg * EMB + (tid & 31) * 4);
            const int kb = (tid & 31) * 4;
            const int idx = (e * 128 + kb) ^ ((e & 7) << 3);
            f16x4 h4 = {(_Float16)v.x, (_Float16)v.y, (_Float16)v.z, (_Float16)v.w};
            *(f16x4*)&sX[idx] = h4;
        }
        __syncthreads();

#pragma unroll
        for (int mth = 0; mth < 2; ++mth) {
            f32x4 hac[2][2];
#pragma unroll
            for (int mi = 0; mi < 2; ++mi)
#pragma unroll
                for (int nt = 0; nt < 2; ++nt) hac[mi][nt] = 0.f;

#pragma unroll
            for (int mi = 0; mi < 2; ++mi) {
                const int m = (mth * 2 + mi) * 16 + lm;
#pragma unroll
                for (int ks = 0; ks < 4; ++ks) {
                    const int xi = (m * 128 + ks * 32 + lq * 8) ^ ((m & 7) << 3);
                    const f16x8 xh = *(const f16x8*)&sX[xi];
#pragma unroll
                    for (int nt = 0; nt < 2; ++nt) {
                        hac[mi][nt] = __builtin_amdgcn_mfma_f32_16x16x32_f16(xh, wh[ks][nt], hac[mi][nt], 0, 0, 0);
                        hac[mi][nt] = __builtin_amdgcn_mfma_f32_16x16x32_f16(xh, wl[ks][nt], hac[mi][nt], 0, 0, 0);
                    }
                }
            }
#pragma unroll
            for (int mi = 0; mi < 2; ++mi) {
                const int rb = base + (mth * 2 + mi) * 16 + lq * 4;
#pragma unroll
                for (int r = 0; r < 4; ++r) {
                    const int rowg = rb + r;
                    if (rowg < M) {
                        Y[(size_t)rowg * EMB + col0] = silu_f(hac[mi][0][r] + b0);
                        Y[(size_t)rowg * EMB + col1] = silu_f(hac[mi][1][r] + b1);
                    }
                }
            }
        }
    }
}

// ---------------------------------------------------------------------------
// Fused layer-3 + final projection: out[row] = (silu(X@W3+b3) @ Wf) * cf.
// ---------------------------------------------------------------------------
__global__ __launch_bounds__(256, 2)
void layer3_final_kernel(const float* __restrict__ X,
                         const float* __restrict__ W,
                         const float* __restrict__ b,
                         const float* __restrict__ Wf,
                         const float* __restrict__ cf,
                         float* __restrict__ out, int M)
{
    __shared__ _Float16 sX[64 * 128];
    __shared__ float    sOut[128];

    const int tid  = threadIdx.x;
    const int w    = tid >> 6;
    const int lane = tid & 63;
    const int lq   = lane >> 4;
    const int lm   = lane & 15;

    const int col0 = w * 32 + lm;
    const int col1 = col0 + 16;
    const float b0 = b[col0], b1 = b[col1];
    const float wf0 = Wf[col0], wf1 = Wf[col1];
    const float cfv = cf[0];

    if (tid < 128) sOut[tid] = 0.f;

    f16x8 wh[4][2], wl[4][2];
#pragma unroll
    for (int ks = 0; ks < 4; ++ks)
#pragma unroll
        for (int nt = 0; nt < 2; ++nt) {
            const int n = w * 32 + nt * 16 + lm;
            f16x8 h8, l8;
#pragma unroll
            for (int j = 0; j < 8; ++j) {
                const int k = ks * 32 + lq * 8 + j;
                const float v = W[k * EMB + n];
                const _Float16 hv = (_Float16)v;
                h8[j] = hv;
                l8[j] = (_Float16)(v - (float)hv);
            }
            wh[ks][nt] = h8;
            wl[ks][nt] = l8;
        }

#pragma unroll
    for (int sub = 0; sub < 2; ++sub) {
        const int base = blockIdx.x * 128 + sub * 64;
        __syncthreads();
#pragma unroll
        for (int i = 0; i < 8; ++i) {
            const int e = (tid >> 5) + i * 8;
            const int rowg = min(base + e, M - 1);
            const float4 v = *(const float4*)(X + (size_t)rowg * EMB + (tid & 31) * 4);
            const int kb = (tid & 31) * 4;
            const int idx = (e * 128 + kb) ^ ((e & 7) << 3);
            f16x4 h4 = {(_Float16)v.x, (_Float16)v.y, (_Float16)v.z, (_Float16)v.w};
            *(f16x4*)&sX[idx] = h4;
        }
        __syncthreads();

#pragma unroll
        for (int mth = 0; mth < 2; ++mth) {
            f32x4 hac[2][2];
#pragma unroll
            for (int mi = 0; mi < 2; ++mi)
#pragma unroll
                for (int nt = 0; nt < 2; ++nt) hac[mi][nt] = 0.f;

#pragma unroll
            for (int mi = 0; mi < 2; ++mi) {
                const int m = (mth * 2 + mi) * 16 + lm;
#pragma unroll
                for (int ks = 0; ks < 4; ++ks) {
                    const int xi = (m * 128 + ks * 32 + lq * 8) ^ ((m & 7) << 3);
                    const f16x8 xh = *(const f16x8*)&sX[xi];
#pragma unroll
                    for (int nt = 0; nt < 2; ++nt) {
                        hac[mi][nt] = __builtin_amdgcn_mfma_f32_16x16x32_f16(xh, wh[ks][nt], hac[mi][nt], 0, 0, 0);
                        hac[mi][nt] = __builtin_amdgcn_mfma_f32_16x16x32_f16(xh, wl[ks][nt], hac[mi][nt], 0, 0, 0);
                    }
                }
            }
#pragma unroll
            for (int mi = 0; mi < 2; ++mi) {
                const int lrow = sub * 64 + (mth * 2 + mi) * 16 + lq * 4;
#pragma unroll
                for (int r = 0; r < 4; ++r) {
                    const float o0 = silu_f(hac[mi][0][r] + b0);
                    const float o1 = silu_f(hac[mi][1][r] + b1);
                    float p = o0 * wf0 + o1 * wf1;
#pragma unroll
                    for (int off = 1; off < 16; off <<= 1)
                        p += __shfl_xor(p, off);
                    if (lm == 0 && base + (mth * 2 + mi) * 16 + lq * 4 + r < M)
                        atomicAdd(&sOut[lrow + r], p);
                }
            }
        }
    }

    __syncthreads();
    if (tid < 128) {
        const int rowg = blockIdx.x * 128 + tid;
        if (rowg < M) out[rowg] = sOut[tid] * cfv;
    }
}

extern "C" void kernel_launch(void* const* d_in, const int* in_sizes, int n_in,
                              void* d_out, int out_size, void* d_ws, size_t ws_size,
                              hipStream_t stream) {
    const float* x    = (const float*)d_in[0];
    const float* rbf  = (const float*)d_in[1];
    const int*   idnb = (const int*)  d_in[2];
    // d_in[3] = n_atoms (fixed 50000)
    const float* Wx   = (const float*)d_in[4];
    const float* bx   = (const float*)d_in[5];
    const float* Wr   = (const float*)d_in[6];
    const float* brf  = (const float*)d_in[7];
    const float* W1   = (const float*)d_in[8];
    const float* b1   = (const float*)d_in[9];
    const float* W2   = (const float*)d_in[10];
    const float* b2   = (const float*)d_in[11];
    const float* W3   = (const float*)d_in[12];
    const float* b3   = (const float*)d_in[13];
    const float* Wf   = (const float*)d_in[14];
    const float* c_a  = (const float*)d_in[15];
    const float* c_b  = (const float*)d_in[16];
    const float* c_x  = (const float*)d_in[17];
    const float* c_f  = (const float*)d_in[18];

    float* out = (float*)d_out;
    float* acc = (float*)d_ws;                        // [NATOMS][128] f32
    float* buf = acc + (size_t)NATOMS * EMB;          // [NATOMS][128] f32
    // CSR scratch inside buf (dead before layer 1 writes buf)
    int* eidx    = (int*)buf;                         // 1M
    int* counts  = eidx + E_TOTAL;                    // NATOMS
    int* row_ptr = counts + NATOMS;                   // NATOMS+1
    int* cursor  = row_ptr + NATOMS + 1;              // NATOMS
    int* bsums   = cursor + NATOMS;                   // NBLK

    hipMemsetAsync(counts, 0, NATOMS * sizeof(int), stream);

    hist_kernel<<<(E_TOTAL + 255) / 256, 256, 0, stream>>>(idnb, counts);
    scan1_kernel<<<NBLK, 256, 0, stream>>>(counts, row_ptr, bsums);
    scan2_kernel<<<1, 256, 0, stream>>>(bsums);
    scan3_kernel<<<NBLK, 256, 0, stream>>>(bsums, row_ptr, cursor);
    scatter_kernel<<<(E_TOTAL + 255) / 256, 256, 0, stream>>>(idnb, cursor, eidx);

    edge_kernel<<<NATOMS / APB, 256, 0, stream>>>(x, rbf, eidx, row_ptr,
                                                  Wx, bx, Wr, brf,
                                                  c_a, c_b, c_x, acc);

    const int ltiles = (NATOMS + 127) / 128;          // 391
    layer_kernel<<<ltiles, 256, 0, stream>>>(acc, W1, b1, buf, NATOMS);
    layer_kernel<<<ltiles, 256, 0, stream>>>(buf, W2, b2, acc, NATOMS);
    layer3_final_kernel<<<ltiles, 256, 0, stream>>>(acc, W3, b3, Wf, c_f, out, NATOMS);
}

// Round 14
// 380.092 us; speedup vs baseline: 1.1316x; 1.1316x over previous
//
#include <hip/hip_runtime.h>

#define E_TOTAL 1000000
#define EMB     128
#define NRBF    16
#define NATOMS  50000
#define APB     40                         // atoms per block (50000 = 40*1250)
#define NBLK    ((NATOMS + 255) / 256)     // scan blocks

typedef _Float16 f16x8 __attribute__((ext_vector_type(8)));
typedef _Float16 f16x4 __attribute__((ext_vector_type(4)));
typedef float    f32x4 __attribute__((ext_vector_type(4)));

__device__ __forceinline__ float silu_f(float v) {
    return v * (1.0f / (1.0f + __expf(-v)));
}

// LDS row e holds sorted edge sigma(e): lane-quarter lq's C-rows across the
// 4 mt steps then cover sorted positions lq*16..lq*16+15 consecutively.
__device__ __forceinline__ int sigma64(int e) {
    return (((e & 15) >> 2) << 4) + ((e >> 4) << 2) + (e & 3);
}

// ---------------------------------------------------------------------------
// CSR build: counting sort of edge ids by destination atom.
// ---------------------------------------------------------------------------
__global__ __launch_bounds__(256)
void hist_kernel(const int* __restrict__ idnb, int* __restrict__ counts) {
    const int e = blockIdx.x * 256 + threadIdx.x;
    if (e < E_TOTAL) atomicAdd(&counts[idnb[e]], 1);
}

__global__ __launch_bounds__(256)
void scan1_kernel(const int* __restrict__ counts, int* __restrict__ row_ptr,
                  int* __restrict__ bsums) {
    __shared__ int sd[256];
    const int tid = threadIdx.x;
    const int idx = blockIdx.x * 256 + tid;
    const int v = (idx < NATOMS) ? counts[idx] : 0;
    sd[tid] = v;
    __syncthreads();
#pragma unroll
    for (int off = 1; off < 256; off <<= 1) {
        const int t = (tid >= off) ? sd[tid - off] : 0;
        __syncthreads();
        sd[tid] += t;
        __syncthreads();
    }
    if (idx < NATOMS) row_ptr[idx] = sd[tid] - v;
    if (tid == 255) bsums[blockIdx.x] = sd[255];
}

__global__ __launch_bounds__(256)
void scan2_kernel(int* __restrict__ bsums) {
    __shared__ int sd[256];
    const int tid = threadIdx.x;
    const int v = (tid < NBLK) ? bsums[tid] : 0;
    sd[tid] = v;
    __syncthreads();
#pragma unroll
    for (int off = 1; off < 256; off <<= 1) {
        const int t = (tid >= off) ? sd[tid - off] : 0;
        __syncthreads();
        sd[tid] += t;
        __syncthreads();
    }
    if (tid < NBLK) bsums[tid] = sd[tid] - v;
}

__global__ __launch_bounds__(256)
void scan3_kernel(const int* __restrict__ bsums, int* __restrict__ row_ptr,
                  int* __restrict__ cursor) {
    const int idx = blockIdx.x * 256 + threadIdx.x;
    if (idx < NATOMS) {
        const int r = row_ptr[idx] + bsums[blockIdx.x];
        row_ptr[idx] = r;
        cursor[idx]  = r;
    }
    if (idx == 0) row_ptr[NATOMS] = E_TOTAL;
}

__global__ __launch_bounds__(256)
void scatter_kernel(const int* __restrict__ idnb, int* __restrict__ cursor,
                    int* __restrict__ eidx) {
    const int e = blockIdx.x * 256 + threadIdx.x;
    if (e < E_TOTAL) {
        const int a = idnb[e];
        const int p = atomicAdd(&cursor[a], 1);
        eidx[p] = e;
    }
}

// ---------------------------------------------------------------------------
// MFMA edge kernel (r11 structure, APB=40). Single-buffer LDS (42.6 KB),
// 2-barrier tile loop, sigma-permuted C-rows + carried run-merge + fused
// gate. Rel-atom derived from the block's 40 scalar row_ptr boundaries.
// ---------------------------------------------------------------------------
__global__ __launch_bounds__(256, 2)
void edge_kernel(const float* __restrict__ x,
                 const float* __restrict__ rbf,
                 const int*   __restrict__ eidx,
                 const int*   __restrict__ row_ptr,
                 const float* __restrict__ Wx,
                 const float* __restrict__ bx,
                 const float* __restrict__ Wr,
                 const float* __restrict__ br,
                 const float* __restrict__ c_a,
                 const float* __restrict__ c_b,
                 const float* __restrict__ c_x,
                 float* __restrict__ acc)
{
    __shared__ _Float16 sX[64 * 128];   // 16 KB, XOR-swizzled 8-f16 groups
    __shared__ _Float16 sR[64 * 40];    // 5 KB, stride-40 pad, k>=16 zero
    __shared__ float    sAcc[APB][132]; // 21.1 KB
    __shared__ int      sAid[64];       // rel-atom of sorted pos (tile-local)

    const int tid  = threadIdx.x;
    const int w    = tid >> 6;
    const int lane = tid & 63;
    const int lq   = lane >> 4;
    const int lm   = lane & 15;

    const int aBase = blockIdx.x * APB;

    // scalar row_ptr boundary table (uniform -> SGPRs)
    int rp[APB];
#pragma unroll
    for (int a = 0; a < APB; ++a) rp[a] = row_ptr[aBase + a];
    const int eBeg = rp[0];
    const int eEnd = row_ptr[aBase + APB];
    const int nEdge = eEnd - eBeg;
    const int ntile = (nEdge + 63) >> 6;

    const float ca = c_a[0];
    const float sc = c_b[0] * c_x[0];
    const int col0 = w * 32 + lm;
    const int col1 = col0 + 16;
    const float bx0 = bx[col0], bx1 = bx[col1];
    const float br0 = br[col0], br1 = br[col1];

    // ---- hoist split-W fragments from global, once per block ----
    f16x8 wxh[4][2], wxl[4][2], wrh[2], wrl[2];
#pragma unroll
    for (int ks = 0; ks < 4; ++ks)
#pragma unroll
        for (int nt = 0; nt < 2; ++nt) {
            const int n = w * 32 + nt * 16 + lm;
            f16x8 h8, l8;
#pragma unroll
            for (int j = 0; j < 8; ++j) {
                const int k = ks * 32 + lq * 8 + j;
                const float v = Wx[k * EMB + n];
                const _Float16 hv = (_Float16)v;
                h8[j] = hv;
                l8[j] = (_Float16)(v - (float)hv);
            }
            wxh[ks][nt] = h8;
            wxl[ks][nt] = l8;
        }
#pragma unroll
    for (int nt = 0; nt < 2; ++nt) {
        const int n = w * 32 + nt * 16 + lm;
        f16x8 h8, l8;
#pragma unroll
        for (int j = 0; j < 8; ++j) {
            const int k = lq * 8 + j;
            const float v = (k < NRBF) ? Wr[k * EMB + n] : 0.f;
            const _Float16 hv = (_Float16)v;
            h8[j] = hv;
            l8[j] = (_Float16)(v - (float)hv);
        }
        wrh[nt] = h8;
        wrl[nt] = l8;
    }

    // init LDS: zero accumulator; zero sR k in [16,40)
    for (int f = tid; f < APB * 132; f += 256) ((float*)sAcc)[f] = 0.f;
    for (int f = tid; f < 64 * 24; f += 256)
        sR[(f / 24) * 40 + 16 + (f % 24)] = (_Float16)0.f;

    float4 px[8];
    float4 pr;
    int    prel = -1;

    auto prefetch = [&](int t) {
        const int nb = eBeg + t * 64;
#pragma unroll
        for (int i = 0; i < 8; ++i) {
            const int e = (tid >> 5) + i * 8;            // LDS row
            const int eid = eidx[min(nb + sigma64(e), eEnd - 1)];
            px[i] = *(const float4*)(x + (size_t)eid * EMB + (tid & 31) * 4);
        }
        {
            const int er = tid >> 2;                     // LDS row (rbf)
            const int eid = eidx[min(nb + sigma64(er), eEnd - 1)];
            pr = *(const float4*)(rbf + (size_t)eid * NRBF + (tid & 3) * 4);
        }
        // rel-atom of sorted position nb+tid from scalar boundaries
        if (tid < 64) {
            const int pos = nb + tid;
            if (pos >= eEnd) {
                prel = -1;
            } else {
                int rel = 0;
#pragma unroll
                for (int a = 1; a < APB; ++a) rel += (pos >= rp[a]) ? 1 : 0;
                prel = rel;
            }
        }
    };

    auto write_lds = [&]() {
#pragma unroll
        for (int i = 0; i < 8; ++i) {
            const int e = (tid >> 5) + i * 8;
            const int kb = (tid & 31) * 4;
            const int idx = (e * 128 + kb) ^ ((e & 7) << 3);
            f16x4 h4 = {(_Float16)px[i].x, (_Float16)px[i].y,
                        (_Float16)px[i].z, (_Float16)px[i].w};
            *(f16x4*)&sX[idx] = h4;
        }
        {
            const int er = tid >> 2;
            const int kb = (tid & 3) * 4;
            f16x4 r4 = {(_Float16)(pr.x * ca), (_Float16)(pr.y * ca),
                        (_Float16)(pr.z * ca), (_Float16)(pr.w * ca)};
            *(f16x4*)&sR[er * 40 + kb] = r4;
        }
        if (tid < 64) sAid[tid] = prel;
    };

    if (ntile > 0) prefetch(0);

    for (int t = 0; t < ntile; ++t) {
        __syncthreads();                 // prev tile's readers (or init) done
        write_lds();
        __syncthreads();                 // tile t visible
        if (t + 1 < ntile) prefetch(t + 1);   // in flight during compute

        // run-merge state carried across the whole tile (16-edge span/lane)
        int   curA = -2;
        float a0v = 0.f, a1v = 0.f;

        auto epi = [&](const f32x4 hac[2], const f32x4 gac[2], int mt) {
            const int pbase = lq * 16 + mt * 4;
            float v0[4], v1[4];
#pragma unroll
            for (int r = 0; r < 4; ++r) {
                const float g0 = gac[0][r] + br0, h0 = hac[0][r] + bx0;
                const float g1 = gac[1][r] + br1, h1 = hac[1][r] + bx1;
                const float d0 = (1.f + __expf(-g0)) * (1.f + __expf(-h0));
                const float d1 = (1.f + __expf(-g1)) * (1.f + __expf(-h1));
                v0[r] = sc * g0 * h0 * __builtin_amdgcn_rcpf(d0);
                v1[r] = sc * g1 * h1 * __builtin_amdgcn_rcpf(d1);
            }
#pragma unroll
            for (int r = 0; r < 4; ++r) {
                const int rel = sAid[pbase + r];
                if (rel != curA) {                  // rarely taken (run ~20)
                    if (curA >= 0) {
                        atomicAdd(&sAcc[curA][col0], a0v);
                        atomicAdd(&sAcc[curA][col1], a1v);
                    }
                    curA = rel; a0v = 0.f; a1v = 0.f;
                }
                a0v += v0[r];
                a1v += v1[r];
            }
        };

        auto mfma_mt = [&](f32x4 hac[2], f32x4 gac[2], int mt) {
#pragma unroll
            for (int nt = 0; nt < 2; ++nt) { hac[nt] = 0.f; gac[nt] = 0.f; }
            const int m = mt * 16 + lm;
            const f16x8 rh = *(const f16x8*)&sR[m * 40 + lq * 8];
#pragma unroll
            for (int nt = 0; nt < 2; ++nt) {
                gac[nt] = __builtin_amdgcn_mfma_f32_16x16x32_f16(rh, wrh[nt], gac[nt], 0, 0, 0);
                gac[nt] = __builtin_amdgcn_mfma_f32_16x16x32_f16(rh, wrl[nt], gac[nt], 0, 0, 0);
            }
#pragma unroll
            for (int ks = 0; ks < 4; ++ks) {
                const int xi = (m * 128 + ks * 32 + lq * 8) ^ ((m & 7) << 3);
                const f16x8 xh = *(const f16x8*)&sX[xi];
#pragma unroll
                for (int nt = 0; nt < 2; ++nt) {
                    hac[nt] = __builtin_amdgcn_mfma_f32_16x16x32_f16(xh, wxh[ks][nt], hac[nt], 0, 0, 0);
                    hac[nt] = __builtin_amdgcn_mfma_f32_16x16x32_f16(xh, wxl[ks][nt], hac[nt], 0, 0, 0);
                }
            }
        };

        // 2-mt groups: two independent MFMA chains in flight per epilogue pair
#pragma unroll
        for (int g = 0; g < 2; ++g) {
            f32x4 hacA[2], gacA[2], hacB[2], gacB[2];
            mfma_mt(hacA, gacA, g * 2);
            mfma_mt(hacB, gacB, g * 2 + 1);
            epi(hacA, gacA, g * 2);
            epi(hacB, gacB, g * 2 + 1);
        }

        if (curA >= 0) {                            // final flush per tile
            atomicAdd(&sAcc[curA][col0], a0v);
            atomicAdd(&sAcc[curA][col1], a1v);
        }
    }

    __syncthreads();   // sAcc atomics (or zero-init) visible
#pragma unroll
    for (int it = 0; it < 3; ++it) {
        const int r = (tid >> 4) + it * 16;
        if (r < APB) {
            const int c = (tid & 15) * 8;
            float* dst = acc + (size_t)(aBase + r) * EMB + c;
            *(float4*)(dst)     = *(const float4*)&sAcc[r][c];
            *(float4*)(dst + 4) = *(const float4*)&sAcc[r][c + 4];
        }
    }
}

// ---------------------------------------------------------------------------
// Fused atom MLP: one block owns 128 rows; L1 -> L2 -> L3 -> final dot all
// in-block, intermediates ping-pong between two f16 LDS buffers (same
// per-layer f16 input rounding as the unfused path). W frags re-hoisted per
// layer stage (unroll 1 keeps one W set live).
// ---------------------------------------------------------------------------
__global__ __launch_bounds__(256, 2)
void mlp_fused_kernel(const float* __restrict__ X,
                      const float* __restrict__ W1, const float* __restrict__ b1,
                      const float* __restrict__ W2, const float* __restrict__ b2,
                      const float* __restrict__ W3, const float* __restrict__ b3,
                      const float* __restrict__ Wf, const float* __restrict__ cf,
                      float* __restrict__ out, int M)
{
    __shared__ _Float16 sA[128 * 128];  // 32 KB
    __shared__ _Float16 sB[128 * 128];  // 32 KB
    __shared__ float    sOut[128];

    const int tid  = threadIdx.x;
    const int w    = tid >> 6;
    const int lane = tid & 63;
    const int lq   = lane >> 4;
    const int lm   = lane & 15;

    const int base = blockIdx.x * 128;
    const int col0 = w * 32 + lm;
    const int col1 = col0 + 16;
    const float wf0 = Wf[col0], wf1 = Wf[col1];
    const float cfv = cf[0];

    if (tid < 128) sOut[tid] = 0.f;

    // stage X (f32 global) -> sA (f16, XOR-swizzled)
#pragma unroll
    for (int i = 0; i < 16; ++i) {
        const int e = (tid >> 5) + i * 8;            // 0..127
        const int row = min(base + e, M - 1);
        const float4 v = *(const float4*)(X + (size_t)row * EMB + (tid & 31) * 4);
        const int kb = (tid & 31) * 4;
        const int idx = (e * 128 + kb) ^ ((e & 7) << 3);
        f16x4 h4 = {(_Float16)v.x, (_Float16)v.y, (_Float16)v.z, (_Float16)v.w};
        *(f16x4*)&sA[idx] = h4;
    }
    __syncthreads();

    const float* Ws[3] = {W1, W2, W3};
    const float* bs[3] = {b1, b2, b3};

#pragma unroll 1
    for (int L = 0; L < 3; ++L) {
        const _Float16* sIn   = (L & 1) ? sB : sA;
        _Float16*       sDst  = (L & 1) ? sA : sB;
        const float*    W     = Ws[L];
        const float     bb0   = bs[L][col0];
        const float     bb1   = bs[L][col1];

        // hoist split-W fragments for this layer
        f16x8 wh[4][2], wl[4][2];
#pragma unroll
        for (int ks = 0; ks < 4; ++ks)
#pragma unroll
            for (int nt = 0; nt < 2; ++nt) {
                const int n = w * 32 + nt * 16 + lm;
                f16x8 h8, l8;
#pragma unroll
                for (int j = 0; j < 8; ++j) {
                    const int k = ks * 32 + lq * 8 + j;
                    const float v = W[k * EMB + n];
                    const _Float16 hv = (_Float16)v;
                    h8[j] = hv;
                    l8[j] = (_Float16)(v - (float)hv);
                }
                wh[ks][nt] = h8;
                wl[ks][nt] = l8;
            }

#pragma unroll
        for (int sub = 0; sub < 2; ++sub) {
#pragma unroll
            for (int mth = 0; mth < 2; ++mth) {
                f32x4 hac[2][2];
#pragma unroll
                for (int mi = 0; mi < 2; ++mi)
#pragma unroll
                    for (int nt = 0; nt < 2; ++nt) hac[mi][nt] = 0.f;

#pragma unroll
                for (int mi = 0; mi < 2; ++mi) {
                    const int m = sub * 64 + (mth * 2 + mi) * 16 + lm;
#pragma unroll
                    for (int ks = 0; ks < 4; ++ks) {
                        const int xi = (m * 128 + ks * 32 + lq * 8) ^ ((m & 7) << 3);
                        const f16x8 xh = *(const f16x8*)&sIn[xi];
#pragma unroll
                        for (int nt = 0; nt < 2; ++nt) {
                            hac[mi][nt] = __builtin_amdgcn_mfma_f32_16x16x32_f16(xh, wh[ks][nt], hac[mi][nt], 0, 0, 0);
                            hac[mi][nt] = __builtin_amdgcn_mfma_f32_16x16x32_f16(xh, wl[ks][nt], hac[mi][nt], 0, 0, 0);
                        }
                    }
                }

#pragma unroll
                for (int mi = 0; mi < 2; ++mi) {
                    const int rowl = sub * 64 + (mth * 2 + mi) * 16 + lq * 4;
                    if (L < 2) {
                        // silu -> f16 -> swizzled LDS (next layer's input)
#pragma unroll
                        for (int r = 0; r < 4; ++r) {
                            const float o0 = silu_f(hac[mi][0][r] + bb0);
                            const float o1 = silu_f(hac[mi][1][r] + bb1);
                            const int rw = rowl + r;
                            sDst[(rw * 128 + col0) ^ ((rw & 7) << 3)] = (_Float16)o0;
                            sDst[(rw * 128 + col1) ^ ((rw & 7) << 3)] = (_Float16)o1;
                        }
                    } else {
                        // final: dot with Wf, 16-lane reduce, accumulate sOut
#pragma unroll
                        for (int r = 0; r < 4; ++r) {
                            const float o0 = silu_f(hac[mi][0][r] + bb0);
                            const float o1 = silu_f(hac[mi][1][r] + bb1);
                            float p = o0 * wf0 + o1 * wf1;
#pragma unroll
                            for (int off = 1; off < 16; off <<= 1)
                                p += __shfl_xor(p, off);
                            if (lm == 0 && base + rowl + r < M)
                                atomicAdd(&sOut[rowl + r], p);
                        }
                    }
                }
            }
        }
        __syncthreads();   // layer outputs visible (or sOut atomics done)
    }

    if (tid < 128) {
        const int row = base + tid;
        if (row < M) out[row] = sOut[tid] * cfv;
    }
}

extern "C" void kernel_launch(void* const* d_in, const int* in_sizes, int n_in,
                              void* d_out, int out_size, void* d_ws, size_t ws_size,
                              hipStream_t stream) {
    const float* x    = (const float*)d_in[0];
    const float* rbf  = (const float*)d_in[1];
    const int*   idnb = (const int*)  d_in[2];
    // d_in[3] = n_atoms (fixed 50000)
    const float* Wx   = (const float*)d_in[4];
    const float* bx   = (const float*)d_in[5];
    const float* Wr   = (const float*)d_in[6];
    const float* brf  = (const float*)d_in[7];
    const float* W1   = (const float*)d_in[8];
    const float* b1   = (const float*)d_in[9];
    const float* W2   = (const float*)d_in[10];
    const float* b2   = (const float*)d_in[11];
    const float* W3   = (const float*)d_in[12];
    const float* b3   = (const float*)d_in[13];
    const float* Wf   = (const float*)d_in[14];
    const float* c_a  = (const float*)d_in[15];
    const float* c_b  = (const float*)d_in[16];
    const float* c_x  = (const float*)d_in[17];
    const float* c_f  = (const float*)d_in[18];

    float* out = (float*)d_out;
    float* acc = (float*)d_ws;                        // [NATOMS][128] f32
    float* buf = acc + (size_t)NATOMS * EMB;          // scratch region
    // CSR scratch inside buf (dead once edge_kernel completes)
    int* eidx    = (int*)buf;                         // 1M
    int* counts  = eidx + E_TOTAL;                    // NATOMS
    int* row_ptr = counts + NATOMS;                   // NATOMS+1
    int* cursor  = row_ptr + NATOMS + 1;              // NATOMS
    int* bsums   = cursor + NATOMS;                   // NBLK

    hipMemsetAsync(counts, 0, NATOMS * sizeof(int), stream);

    hist_kernel<<<(E_TOTAL + 255) / 256, 256, 0, stream>>>(idnb, counts);
    scan1_kernel<<<NBLK, 256, 0, stream>>>(counts, row_ptr, bsums);
    scan2_kernel<<<1, 256, 0, stream>>>(bsums);
    scan3_kernel<<<NBLK, 256, 0, stream>>>(bsums, row_ptr, cursor);
    scatter_kernel<<<(E_TOTAL + 255) / 256, 256, 0, stream>>>(idnb, cursor, eidx);

    edge_kernel<<<NATOMS / APB, 256, 0, stream>>>(x, rbf, eidx, row_ptr,
                                                  Wx, bx, Wr, brf,
                                                  c_a, c_b, c_x, acc);

    mlp_fused_kernel<<<(NATOMS + 127) / 128, 256, 0, stream>>>(
        acc, W1, b1, W2, b2, W3, b3, Wf, c_f, out, NATOMS);
}